// Round 1
// baseline (876.462 us; speedup 1.0000x reference)
//
#include <hip/hip_runtime.h>
#include <math.h>

#define NROWS 32768
#define DIM   256
#define KCODES 1024

// ---- ws layout (bytes) ----
//      0 : double loss accumulator
//     16 : se[1024]   f32  (np-exact codebook row sum-of-squares)
//   4112 : sacb[1024] f32  (codebook abs-sum scratch, unused)
//   8208 : sx[32768]  f32  (np-exact x row sum-of-squares)
// 139280 : sa[32768]  f32  (x row sum-of-|.|, error-margin input)
// 270352 : cb_bf16[1024*256] ushort (RTNE bf16 codebook)
#define WS_SE    16
#define WS_SACB  4112
#define WS_SX    8208
#define WS_SA    139280
#define WS_CBBF  270352

typedef __attribute__((ext_vector_type(8))) short  short8;
typedef __attribute__((ext_vector_type(4))) float  f32x4;

union U16H { unsigned short u; _Float16 h; };
__device__ __forceinline__ float f16tof32(unsigned short u){ U16H a; a.u = u; return (float)a.h; }
__device__ __forceinline__ unsigned short f32tof16(float f){ U16H a; a.h = (_Float16)f; return a.u; }

__device__ __forceinline__ unsigned short bf16rtne(float f){
    unsigned int u = __float_as_uint(f);
    unsigned int r = (u + 0x7FFFu + ((u >> 16) & 1u)) >> 16;
    return (unsigned short)r;
}

__device__ __forceinline__ void gload_lds16(const void* g, void* l){
    __builtin_amdgcn_global_load_lds(
        (const __attribute__((address_space(1))) void*)g,
        (__attribute__((address_space(3))) void*)l, 16, 0, 0);
}

__global__ void init_ws(double* acc) {
    if (threadIdx.x == 0 && blockIdx.x == 0) *acc = 0.0;
}

// Bit-exact numpy pairwise_sum replication for sum(x^2) per row (unchanged
// instruction sequence for r), plus an order-free sum(|x|) for the margin.
__global__ void rowsq_kernel(const float* __restrict__ src,
                             float* __restrict__ dst,
                             float* __restrict__ dst_abs, int nrows) {
    const int gtid = blockIdx.x * blockDim.x + threadIdx.x;
    const int wave = gtid >> 6;
    const int lane = threadIdx.x & 63;
    const int rowsub = lane >> 4;
    const int agent  = lane & 15;
    const int half   = agent >> 3;
    const int j      = agent & 7;
    const int row = wave * 4 + rowsub;
    if (row >= nrows) return;

    const float* p = src + (size_t)row * DIM + half * 128 + j;
    float x0 = p[0];
    float r  = __fmul_rn(x0, x0);
    float ra = fabsf(x0);
    #pragma unroll
    for (int i = 1; i < 16; ++i) {
        float xi = p[8 * i];
        r  = __fadd_rn(r, __fmul_rn(xi, xi));
        ra += fabsf(xi);
    }
    r = __fadd_rn(r, __shfl_xor(r, 1, 64));  ra += __shfl_xor(ra, 1, 64);
    r = __fadd_rn(r, __shfl_xor(r, 2, 64));  ra += __shfl_xor(ra, 2, 64);
    r = __fadd_rn(r, __shfl_xor(r, 4, 64));  ra += __shfl_xor(ra, 4, 64);
    r = __fadd_rn(r, __shfl_xor(r, 8, 64));  ra += __shfl_xor(ra, 8, 64);
    if (agent == 0) { dst[row] = r; dst_abs[row] = ra; }
}

__global__ void cvt_cb_kernel(const float* __restrict__ cb,
                              unsigned short* __restrict__ dst) {
    int t = blockIdx.x * 256 + threadIdx.x;   // 65536 threads x 4 elems
    float4 v = ((const float4*)cb)[t];
    ushort4 o;
    o.x = bf16rtne(v.x); o.y = bf16rtne(v.y);
    o.z = bf16rtne(v.z); o.w = bf16rtne(v.w);
    ((ushort4*)dst)[t] = o;
}

#define FMA4(A, X, E) do {                                       \
    A.x = fmaf(X.x, E.x, A.x); A.y = fmaf(X.y, E.y, A.y);        \
    A.z = fmaf(X.z, E.z, A.z); A.w = fmaf(X.w, E.w, A.w);        \
} while (0)

// 512 blocks x 64 rows. 4 waves; each wave holds all 64 rows as bf16 MFMA
// A-fragments in registers and owns a 16-code column slice of each staged
// 64-code tile. Scores (f16) buffered per 512-code half in LDS; candidates
// selected with a rigorous bf16-error margin, then rescored with the exact
// fp32 arithmetic chain (same as the verified VALU kernel).
__launch_bounds__(256, 1)
__global__ void vq_mfma(const float* __restrict__ x,
                        const float* __restrict__ cb,
                        const float* __restrict__ sx_arr,
                        const float* __restrict__ sa_arr,
                        const float* __restrict__ se_arr,
                        const unsigned short* __restrict__ cbbf,
                        float* __restrict__ out_q,
                        float* __restrict__ out_idx,
                        double* __restrict__ loss_acc)
{
    __shared__ __align__(16) unsigned short bs[2][64 * 256]; // 65536 B (B dbuf / x-f32 stage)
    __shared__ __align__(16) unsigned short sc[512 * 68];    // 69632 B (f16 scores, 1 half)
    __shared__ __align__(16) float se_l[KCODES];             // 4096 B
    __shared__ float minb[4][64];
    __shared__ float thr[64];
    __shared__ unsigned int cnt[64];
    __shared__ unsigned int cand[64][16];
    __shared__ unsigned long long win[64];
    __shared__ unsigned int wcode[64];

    const int tid  = threadIdx.x;
    const int w    = tid >> 6;
    const int lane = tid & 63;
    const int cc   = lane & 15;
    const int g    = lane >> 4;
    const int n0   = blockIdx.x * 64;

    if (tid < 64) { cnt[tid] = 0u; win[tid] = ~0ull; }
    { float4 v = ((const float4*)se_arr)[tid]; *(float4*)(se_l + tid * 4) = v; }

    // ---- Phase 1: stage 64 x-rows fp32 into bs, XOR-swizzled (coalesced) ----
    float* xsf = (float*)&bs[0][0];
    #pragma unroll
    for (int i = 0; i < 16; ++i) {
        int f4  = tid + 256 * i;            // 0..4095 float4s
        int row = f4 >> 6;
        float4 v = ((const float4*)x)[n0 * 64 + f4];
        int phys = (f4 * 16) ^ ((row & 7) << 4);
        *(float4*)((char*)xsf + phys) = v;
    }
    __syncthreads();

    // ---- Phase 2: A fragments (all 64 rows x 256 k) -> registers as bf16 ----
    // mfma_f32_16x16x32_bf16 A: lane holds row = lane&15, k = 32*s + 8*(lane>>4)+e
    short8 afrag[4][8];
    #pragma unroll
    for (int rt = 0; rt < 4; ++rt) {
        const int row = rt * 16 + cc;
        const int swz = (row & 7) << 4;
        #pragma unroll
        for (int s = 0; s < 8; ++s) {
            int L = row * 1024 + s * 128 + g * 32;
            float4 a = *(const float4*)((const char*)xsf + ((L     ) ^ swz));
            float4 b = *(const float4*)((const char*)xsf + ((L + 16) ^ swz));
            short8 f;
            f[0] = (short)bf16rtne(a.x); f[1] = (short)bf16rtne(a.y);
            f[2] = (short)bf16rtne(a.z); f[3] = (short)bf16rtne(a.w);
            f[4] = (short)bf16rtne(b.x); f[5] = (short)bf16rtne(b.y);
            f[6] = (short)bf16rtne(b.z); f[7] = (short)bf16rtne(b.w);
            afrag[rt][s] = f;
        }
    }
    __syncthreads();

    // ---- B staging: per-lane pre-swizzled source offsets (rule: linear LDS
    //      dest + inverse-swizzled source + swizzled read) ----
    int boff[8];
    #pragma unroll
    for (int i = 0; i < 8; ++i) {
        int ch   = w * 8 + i;
        int lo   = ch * 1024 + lane * 16;
        int code = ch * 2 + (lane >> 5);
        boff[i] = lo ^ ((code & 7) << 4);
    }
    {
        const char* gsrc = (const char*)cbbf;
        #pragma unroll
        for (int i = 0; i < 8; ++i)
            gload_lds16(gsrc + boff[i], (char*)&bs[0][0] + (w * 8 + i) * 1024);
    }
    __syncthreads();

    float minr[4][4];
    #pragma unroll
    for (int rt = 0; rt < 4; ++rt) {
        #pragma unroll
        for (int r = 0; r < 4; ++r) minr[rt][r] = INFINITY;
    }

    const int swzb = (cc & 7) << 4;
    const int L0   = (w * 16 + cc) * 512 + g * 16;
    const f32x4 fz = {0.f, 0.f, 0.f, 0.f};

    for (int st = 0; st < 16; ++st) {
        // prefetch next 64-code tile into the other buffer
        if (st < 15) {
            const char* gsrc = (const char*)cbbf + (st + 1) * 32768;
            char* ldst = (char*)&bs[(st + 1) & 1][0];
            #pragma unroll
            for (int i = 0; i < 8; ++i)
                gload_lds16(gsrc + boff[i], ldst + (w * 8 + i) * 1024);
        }
        // compute: 8 K-steps x 4 row-tiles (each B read feeds 4 MFMAs)
        f32x4 acc[4];
        #pragma unroll
        for (int rt = 0; rt < 4; ++rt) acc[rt] = fz;
        const char* bb = (const char*)&bs[st & 1][0];
        #pragma unroll
        for (int s = 0; s < 8; ++s) {
            short8 bf = *(const short8*)(bb + ((L0 + s * 64) ^ swzb));
            #pragma unroll
            for (int rt = 0; rt < 4; ++rt)
                acc[rt] = __builtin_amdgcn_mfma_f32_16x16x32_bf16(afrag[rt][s], bf, acc[rt], 0, 0, 0);
        }
        // epilogue: s = se - 2*dot, running min + f16 score store
        // C layout: col = lane&15 (code), row = 4*(lane>>4)+reg
        const float sec = se_l[st * 64 + w * 16 + cc];
        const int csc = (st & 7) * 64 + w * 16 + cc;
        #pragma unroll
        for (int rt = 0; rt < 4; ++rt) {
            float s0 = fmaf(-2.f, acc[rt][0], sec);
            float s1 = fmaf(-2.f, acc[rt][1], sec);
            float s2 = fmaf(-2.f, acc[rt][2], sec);
            float s3 = fmaf(-2.f, acc[rt][3], sec);
            minr[rt][0] = fminf(minr[rt][0], s0);
            minr[rt][1] = fminf(minr[rt][1], s1);
            minr[rt][2] = fminf(minr[rt][2], s2);
            minr[rt][3] = fminf(minr[rt][3], s3);
            uint2 pk;
            pk.x = (unsigned int)f32tof16(s0) | ((unsigned int)f32tof16(s1) << 16);
            pk.y = (unsigned int)f32tof16(s2) | ((unsigned int)f32tof16(s3) << 16);
            *(uint2*)((char*)sc + csc * 136 + rt * 32 + g * 8) = pk;
        }
        __syncthreads();

        // ---- interlude after each 512-code half: min -> threshold -> scan ----
        if ((st & 7) == 7) {
            const int half = st >> 3;
            #pragma unroll
            for (int rt = 0; rt < 4; ++rt) {
                #pragma unroll
                for (int r = 0; r < 4; ++r) {
                    float v = minr[rt][r];
                    v = fminf(v, __shfl_xor(v, 1, 64));
                    v = fminf(v, __shfl_xor(v, 2, 64));
                    v = fminf(v, __shfl_xor(v, 4, 64));
                    v = fminf(v, __shfl_xor(v, 8, 64));
                    if (cc == 0) minb[w][rt * 16 + g * 4 + r] = v;
                }
            }
            __syncthreads();
            if (tid < 64) {
                float mm = fminf(fminf(minb[0][tid], minb[1][tid]),
                                 fminf(minb[2][tid], minb[3][tid]));
                // margin: 2*(bf16 dot err bound) + f16 quant + fp32 ordering slack
                float sa = sa_arr[n0 + tid];
                thr[tid] = mm + fmaf(sa, 1.8e-5f, 5.0e-4f);
            }
            __syncthreads();
            {
                const int rp = tid & 31;     // row pair
                const int c0 = tid >> 5;     // code slice 0..7
                const float t0 = thr[2 * rp], t1 = thr[2 * rp + 1];
                for (int j = 0; j < 64; ++j) {
                    int c = c0 + 8 * j;
                    unsigned int v = *(const unsigned int*)((const char*)sc + c * 136 + rp * 4);
                    float f0 = f16tof32((unsigned short)(v & 0xFFFFu));
                    float f1 = f16tof32((unsigned short)(v >> 16));
                    if (f0 <= t0) {
                        unsigned int p = atomicAdd(&cnt[2 * rp], 1u);
                        if (p < 16u) cand[2 * rp][p] = (unsigned int)(half * 512 + c);
                    }
                    if (f1 <= t1) {
                        unsigned int p = atomicAdd(&cnt[2 * rp + 1], 1u);
                        if (p < 16u) cand[2 * rp + 1][p] = (unsigned int)(half * 512 + c);
                    }
                }
            }
            __syncthreads();
        }
    }

    // ---- exact fp32 rescore (identical arithmetic chain; tie -> lower code) ----
    {
        const int r  = tid >> 2;
        const int sl = tid & 3;
        const unsigned int n = cnt[r];
        const bool ovf = (n > 16u);
        const unsigned int total = ovf ? (unsigned int)KCODES : n;
        const float sxr = sx_arr[n0 + r];
        const float4* xr  = (const float4*)x + (size_t)(n0 + r) * 64;
        const float4* cb4 = (const float4*)cb;
        for (unsigned int j = sl; j < total; j += 4) {
            unsigned int code = ovf ? j : cand[r][j];
            const float4* er = cb4 + (size_t)code * 64;
            float4 a4 = make_float4(0.f, 0.f, 0.f, 0.f);
            #pragma unroll 8
            for (int m = 0; m < 64; ++m) {
                float4 xv = xr[m];
                float4 ev = er[m];
                FMA4(a4, xv, ev);
            }
            float dot  = (a4.x + a4.y) + (a4.z + a4.w);
            float t    = __fadd_rn(sxr, se_l[code]);
            float dist = __fsub_rn(t, 2.0f * dot);
            unsigned long long pk =
                ((unsigned long long)__float_as_uint(dist) << 32) | (unsigned long long)code;
            atomicMin(&win[r], pk);
        }
    }
    __syncthreads();
    if (tid < 64) {
        unsigned int code = (unsigned int)(win[tid] & 0xFFFFFFFFull);
        wcode[tid] = code;
        out_idx[n0 + tid] = (float)code;
    }
    __syncthreads();

    // ---- outputs (bit-exact straight-through) + fp64 loss partial ----
    double lacc = 0.0;
    {
        const float4* x4  = (const float4*)x;
        const float4* cb4 = (const float4*)cb;
        float4* q4 = (float4*)out_q;
        #pragma unroll
        for (int i = 0; i < 16; ++i) {
            int flat = tid + 256 * i;       // 0..4095
            int row  = flat >> 6;
            int d4   = flat & 63;
            float4 xv = x4[n0 * 64 + flat];
            float4 qv = cb4[(size_t)wcode[row] * 64 + d4];
            float dfx = __fsub_rn(qv.x, xv.x);
            float dfy = __fsub_rn(qv.y, xv.y);
            float dfz = __fsub_rn(qv.z, xv.z);
            float dfw = __fsub_rn(qv.w, xv.w);
            float4 o;
            o.x = __fadd_rn(xv.x, dfx);
            o.y = __fadd_rn(xv.y, dfy);
            o.z = __fadd_rn(xv.z, dfz);
            o.w = __fadd_rn(xv.w, dfw);
            lacc += (double)dfx * dfx + (double)dfy * dfy
                  + (double)dfz * dfz + (double)dfw * dfw;
            q4[n0 * 64 + flat] = o;
        }
    }
    #pragma unroll
    for (int off = 32; off > 0; off >>= 1)
        lacc += __shfl_down(lacc, off, 64);
    if (lane == 0) atomicAdd(loss_acc, lacc);
}

__global__ void finalize_loss(const double* __restrict__ acc,
                              float* __restrict__ out_loss) {
    if (threadIdx.x == 0 && blockIdx.x == 0)
        *out_loss = (float)(*acc / (double)(NROWS * DIM));
}

extern "C" void kernel_launch(void* const* d_in, const int* in_sizes, int n_in,
                              void* d_out, int out_size, void* d_ws, size_t ws_size,
                              hipStream_t stream) {
    const float* x  = (const float*)d_in[0];
    const float* cb = (const float*)d_in[1];
    float* out      = (float*)d_out;
    float* out_q    = out;                        // 8388608 elements
    float* out_idx  = out + (size_t)NROWS * DIM;  // 32768 elements (as float)
    float* out_loss = out_idx + NROWS;            // 1 element

    char* ws = (char*)d_ws;
    double* acc = (double*)ws;
    float* se   = (float*)(ws + WS_SE);
    float* sacb = (float*)(ws + WS_SACB);
    float* sx   = (float*)(ws + WS_SX);
    float* sa   = (float*)(ws + WS_SA);
    unsigned short* cbbf = (unsigned short*)(ws + WS_CBBF);

    init_ws<<<1, 1, 0, stream>>>(acc);
    rowsq_kernel<<<KCODES / 16, 256, 0, stream>>>(cb, se, sacb, KCODES);
    rowsq_kernel<<<NROWS / 16, 256, 0, stream>>>(x, sx, sa, NROWS);
    cvt_cb_kernel<<<256, 256, 0, stream>>>(cb, cbbf);
    vq_mfma<<<NROWS / 64, 256, 0, stream>>>(x, cb, sx, sa, se, cbbf,
                                            out_q, out_idx, acc);
    finalize_loss<<<1, 1, 0, stream>>>(acc, out_loss);
}

// Round 2
// 343.313 us; speedup vs baseline: 2.5529x; 2.5529x over previous
//
#include <hip/hip_runtime.h>
#include <math.h>

#define NROWS 32768
#define DIM   256
#define KCODES 1024
#define RPB   32      // rows per block
#define CANDC 12      // candidate cap per row

// ---- ws layout (bytes) ----
//      0 : double loss accumulator
//     16 : se[1024]   f32  (np-exact codebook row sum-of-squares)
//   4112 : sacb[1024] f32  (codebook abs-sum scratch, unused)
//   8208 : sx[32768]  f32  (np-exact x row sum-of-squares)
// 139280 : sa[32768]  f32  (x row sum-of-|.|, error-margin input)
// 270352 : cb_bf16[1024*256] ushort (RTNE bf16 codebook)
#define WS_SE    16
#define WS_SACB  4112
#define WS_SX    8208
#define WS_SA    139280
#define WS_CBBF  270352

typedef __attribute__((ext_vector_type(8))) short  short8;
typedef __attribute__((ext_vector_type(4))) float  f32x4;

__device__ __forceinline__ unsigned short bf16rtne(float f){
    unsigned int u = __float_as_uint(f);
    return (unsigned short)((u + 0x7FFFu + ((u >> 16) & 1u)) >> 16);
}

__global__ void init_ws(double* acc) {
    if (threadIdx.x == 0 && blockIdx.x == 0) *acc = 0.0;
}

// Bit-exact numpy pairwise_sum replication for sum(x^2) per row, plus an
// order-free sum(|x|) for the error margin.
__global__ void rowsq_kernel(const float* __restrict__ src,
                             float* __restrict__ dst,
                             float* __restrict__ dst_abs, int nrows) {
    const int gtid = blockIdx.x * blockDim.x + threadIdx.x;
    const int wave = gtid >> 6;
    const int lane = threadIdx.x & 63;
    const int rowsub = lane >> 4;
    const int agent  = lane & 15;
    const int half   = agent >> 3;
    const int j      = agent & 7;
    const int row = wave * 4 + rowsub;
    if (row >= nrows) return;

    const float* p = src + (size_t)row * DIM + half * 128 + j;
    float x0 = p[0];
    float r  = __fmul_rn(x0, x0);
    float ra = fabsf(x0);
    #pragma unroll
    for (int i = 1; i < 16; ++i) {
        float xi = p[8 * i];
        r  = __fadd_rn(r, __fmul_rn(xi, xi));
        ra += fabsf(xi);
    }
    r = __fadd_rn(r, __shfl_xor(r, 1, 64));  ra += __shfl_xor(ra, 1, 64);
    r = __fadd_rn(r, __shfl_xor(r, 2, 64));  ra += __shfl_xor(ra, 2, 64);
    r = __fadd_rn(r, __shfl_xor(r, 4, 64));  ra += __shfl_xor(ra, 4, 64);
    r = __fadd_rn(r, __shfl_xor(r, 8, 64));  ra += __shfl_xor(ra, 8, 64);
    if (agent == 0) { dst[row] = r; dst_abs[row] = ra; }
}

__global__ void cvt_cb_kernel(const float* __restrict__ cb,
                              unsigned short* __restrict__ dst) {
    int t = blockIdx.x * 256 + threadIdx.x;   // 65536 threads x 4 elems
    float4 v = ((const float4*)cb)[t];
    ushort4 o;
    o.x = bf16rtne(v.x); o.y = bf16rtne(v.y);
    o.z = bf16rtne(v.z); o.w = bf16rtne(v.w);
    ((ushort4*)dst)[t] = o;
}

#define FMA4(A, X, E) do {                                       \
    A.x = fmaf(X.x, E.x, A.x); A.y = fmaf(X.y, E.y, A.y);        \
    A.z = fmaf(X.z, E.z, A.z); A.w = fmaf(X.w, E.w, A.w);        \
} while (0)

// Occupancy-first MFMA kernel: 1024 blocks x 4 waves, 32 rows/block.
// Each wave: all 32 rows as bf16 A-frags in regs; private 256-code slice;
// B-frags read directly from L2-resident bf16 codebook (no LDS staging).
// Pass A: min tracking. Pass B: deterministic recompute, emit candidates
// within rigorous bf16-error margin. Pass C: exact fp32 rescore (verified
// bit-exact chain). Then straight-through output + fp64 loss.
__launch_bounds__(256, 3)
__global__ void vq_score(const float* __restrict__ x,
                         const float* __restrict__ cb,
                         const float* __restrict__ sx_arr,
                         const float* __restrict__ sa_arr,
                         const float* __restrict__ se_arr,
                         const unsigned short* __restrict__ cbbf,
                         float* __restrict__ out_q,
                         float* __restrict__ out_idx,
                         double* __restrict__ loss_acc)
{
    __shared__ float minw[4][RPB];
    __shared__ float thr[RPB];
    __shared__ unsigned int cnt[RPB];
    __shared__ unsigned int cand[RPB][CANDC];
    __shared__ unsigned long long win[RPB];
    __shared__ unsigned int wcode[RPB];

    const int tid  = threadIdx.x;
    const int w    = tid >> 6;
    const int lane = tid & 63;
    const int cc   = lane & 15;
    const int g    = lane >> 4;
    const int n0   = blockIdx.x * RPB;

    if (tid < RPB) { cnt[tid] = 0u; win[tid] = ~0ull; }

    // ---- A fragments: rows rt*16+cc, k = 32s + 8g + e (verified mapping) ----
    short8 afrag[2][8];
    #pragma unroll
    for (int rt = 0; rt < 2; ++rt) {
        const float4* rp = (const float4*)x + (size_t)(n0 + rt * 16 + cc) * 64;
        #pragma unroll
        for (int s = 0; s < 8; ++s) {
            float4 a = rp[s * 8 + g * 2];
            float4 b = rp[s * 8 + g * 2 + 1];
            short8 f;
            f[0] = (short)bf16rtne(a.x); f[1] = (short)bf16rtne(a.y);
            f[2] = (short)bf16rtne(a.z); f[3] = (short)bf16rtne(a.w);
            f[4] = (short)bf16rtne(b.x); f[5] = (short)bf16rtne(b.y);
            f[6] = (short)bf16rtne(b.z); f[7] = (short)bf16rtne(b.w);
            afrag[rt][s] = f;
        }
    }

    const int cw = w << 8;        // wave's 256-code base
    const f32x4 fz = {0.f, 0.f, 0.f, 0.f};

    // ---- PASS A: score all codes, track per-lane running min ----
    float minr[2][4];
    #pragma unroll
    for (int rt = 0; rt < 2; ++rt)
        #pragma unroll
        for (int r = 0; r < 4; ++r) minr[rt][r] = INFINITY;

    for (int t = 0; t < 16; ++t) {
        const int cbase = cw + t * 16;
        const char* bp = (const char*)cbbf + (size_t)(cbase + cc) * 512 + g * 16;
        f32x4 acc0 = fz, acc1 = fz;
        #pragma unroll
        for (int s = 0; s < 8; ++s) {
            short8 bv = *(const short8*)(bp + s * 64);
            acc0 = __builtin_amdgcn_mfma_f32_16x16x32_bf16(afrag[0][s], bv, acc0, 0, 0, 0);
            acc1 = __builtin_amdgcn_mfma_f32_16x16x32_bf16(afrag[1][s], bv, acc1, 0, 0, 0);
        }
        const float sec = se_arr[cbase + cc];
        #pragma unroll
        for (int r = 0; r < 4; ++r) {
            minr[0][r] = fminf(minr[0][r], fmaf(-2.f, acc0[r], sec));
            minr[1][r] = fminf(minr[1][r], fmaf(-2.f, acc1[r], sec));
        }
    }

    // reduce min across the 16 cc-lanes (row = rt*16 + 4g + r)
    #pragma unroll
    for (int rt = 0; rt < 2; ++rt) {
        #pragma unroll
        for (int r = 0; r < 4; ++r) {
            float v = minr[rt][r];
            v = fminf(v, __shfl_xor(v, 1, 64));
            v = fminf(v, __shfl_xor(v, 2, 64));
            v = fminf(v, __shfl_xor(v, 4, 64));
            v = fminf(v, __shfl_xor(v, 8, 64));
            if (cc == 0) minw[w][rt * 16 + g * 4 + r] = v;
        }
    }
    __syncthreads();
    if (tid < RPB) {
        float mm = fminf(fminf(minw[0][tid], minw[1][tid]),
                         fminf(minw[2][tid], minw[3][tid]));
        // margin: 2*(bf16 input-quant dot error, <= sa*7.7e-6) + f32 chain ulp slack
        thr[tid] = mm + fmaf(sa_arr[n0 + tid], 1.6e-5f, 1.0e-4f);
    }
    __syncthreads();

    // ---- PASS B: deterministic recompute, emit candidates <= thr ----
    float th[2][4];
    #pragma unroll
    for (int rt = 0; rt < 2; ++rt)
        #pragma unroll
        for (int r = 0; r < 4; ++r) th[rt][r] = thr[rt * 16 + g * 4 + r];

    for (int t = 0; t < 16; ++t) {
        const int cbase = cw + t * 16;
        const char* bp = (const char*)cbbf + (size_t)(cbase + cc) * 512 + g * 16;
        f32x4 acc0 = fz, acc1 = fz;
        #pragma unroll
        for (int s = 0; s < 8; ++s) {
            short8 bv = *(const short8*)(bp + s * 64);
            acc0 = __builtin_amdgcn_mfma_f32_16x16x32_bf16(afrag[0][s], bv, acc0, 0, 0, 0);
            acc1 = __builtin_amdgcn_mfma_f32_16x16x32_bf16(afrag[1][s], bv, acc1, 0, 0, 0);
        }
        const float sec = se_arr[cbase + cc];
        #pragma unroll
        for (int r = 0; r < 4; ++r) {
            float s0 = fmaf(-2.f, acc0[r], sec);
            float s1 = fmaf(-2.f, acc1[r], sec);
            if (s0 <= th[0][r]) {
                int row = g * 4 + r;
                unsigned int p = atomicAdd(&cnt[row], 1u);
                if (p < (unsigned)CANDC) cand[row][p] = (unsigned int)(cbase + cc);
            }
            if (s1 <= th[1][r]) {
                int row = 16 + g * 4 + r;
                unsigned int p = atomicAdd(&cnt[row], 1u);
                if (p < (unsigned)CANDC) cand[row][p] = (unsigned int)(cbase + cc);
            }
        }
    }
    __syncthreads();

    // ---- PASS C: exact fp32 rescore of candidates (tie -> lower code) ----
    {
        const int r  = tid >> 3;
        const int sl = tid & 7;
        const unsigned int n = cnt[r];
        const bool ovf = (n > (unsigned)CANDC);
        const unsigned int total = ovf ? (unsigned)KCODES : n;
        const float sxr = sx_arr[n0 + r];
        const float4* xr  = (const float4*)x + (size_t)(n0 + r) * 64;
        const float4* cb4 = (const float4*)cb;
        for (unsigned int j = sl; j < total; j += 8) {
            unsigned int code = ovf ? j : cand[r][j];
            const float4* er = cb4 + (size_t)code * 64;
            float4 a4 = make_float4(0.f, 0.f, 0.f, 0.f);
            #pragma unroll 8
            for (int m = 0; m < 64; ++m) {
                float4 xv = xr[m];
                float4 ev = er[m];
                FMA4(a4, xv, ev);
            }
            float dot  = (a4.x + a4.y) + (a4.z + a4.w);
            float tt   = __fadd_rn(sxr, se_arr[code]);
            float dist = __fsub_rn(tt, 2.0f * dot);
            unsigned long long pk =
                ((unsigned long long)__float_as_uint(dist) << 32) | (unsigned long long)code;
            atomicMin(&win[r], pk);
        }
    }
    __syncthreads();
    if (tid < RPB) {
        unsigned int code = (unsigned int)(win[tid] & 0xFFFFFFFFull);
        wcode[tid] = code;
        out_idx[n0 + tid] = (float)code;
    }
    __syncthreads();

    // ---- outputs (bit-exact straight-through) + fp64 loss partial ----
    double lacc = 0.0;
    {
        const float4* x4  = (const float4*)x;
        const float4* cb4 = (const float4*)cb;
        float4* q4 = (float4*)out_q;
        #pragma unroll
        for (int i = 0; i < 8; ++i) {
            int flat = tid + 256 * i;       // 0..2047 (32 rows x 64 float4)
            int row  = flat >> 6;
            int d4   = flat & 63;
            float4 xv = x4[(size_t)n0 * 64 + flat];
            float4 qv = cb4[(size_t)wcode[row] * 64 + d4];
            float dfx = __fsub_rn(qv.x, xv.x);
            float dfy = __fsub_rn(qv.y, xv.y);
            float dfz = __fsub_rn(qv.z, xv.z);
            float dfw = __fsub_rn(qv.w, xv.w);
            float4 o;
            o.x = __fadd_rn(xv.x, dfx);
            o.y = __fadd_rn(xv.y, dfy);
            o.z = __fadd_rn(xv.z, dfz);
            o.w = __fadd_rn(xv.w, dfw);
            lacc += (double)dfx * dfx + (double)dfy * dfy
                  + (double)dfz * dfz + (double)dfw * dfw;
            q4[(size_t)n0 * 64 + flat] = o;
        }
    }
    #pragma unroll
    for (int off = 32; off > 0; off >>= 1)
        lacc += __shfl_down(lacc, off, 64);
    if (lane == 0) atomicAdd(loss_acc, lacc);
}

__global__ void finalize_loss(const double* __restrict__ acc,
                              float* __restrict__ out_loss) {
    if (threadIdx.x == 0 && blockIdx.x == 0)
        *out_loss = (float)(*acc / (double)(NROWS * DIM));
}

extern "C" void kernel_launch(void* const* d_in, const int* in_sizes, int n_in,
                              void* d_out, int out_size, void* d_ws, size_t ws_size,
                              hipStream_t stream) {
    const float* x  = (const float*)d_in[0];
    const float* cb = (const float*)d_in[1];
    float* out      = (float*)d_out;
    float* out_q    = out;                        // 8388608 elements
    float* out_idx  = out + (size_t)NROWS * DIM;  // 32768 elements (as float)
    float* out_loss = out_idx + NROWS;            // 1 element

    char* ws = (char*)d_ws;
    double* acc = (double*)ws;
    float* se   = (float*)(ws + WS_SE);
    float* sacb = (float*)(ws + WS_SACB);
    float* sx   = (float*)(ws + WS_SX);
    float* sa   = (float*)(ws + WS_SA);
    unsigned short* cbbf = (unsigned short*)(ws + WS_CBBF);

    init_ws<<<1, 1, 0, stream>>>(acc);
    rowsq_kernel<<<KCODES / 16, 256, 0, stream>>>(cb, se, sacb, KCODES);
    rowsq_kernel<<<NROWS / 16, 256, 0, stream>>>(x, sx, sa, NROWS);
    cvt_cb_kernel<<<256, 256, 0, stream>>>(cb, cbbf);
    vq_score<<<NROWS / RPB, 256, 0, stream>>>(x, cb, sx, sa, se, cbbf,
                                              out_q, out_idx, acc);
    finalize_loss<<<1, 1, 0, stream>>>(acc, out_loss);
}

// Round 3
// 269.072 us; speedup vs baseline: 3.2574x; 1.2759x over previous
//
#include <hip/hip_runtime.h>
#include <math.h>

#define NROWS 32768
#define DIM   256
#define KCODES 1024
#define RPB   32      // rows per block
#define CANDC 12      // candidate cap per row

// ---- ws layout (bytes) ----
//      0 : double loss accumulator
//     16 : se[1024]   f32  (np-exact codebook row sum-of-squares)
//   4112 : sacb[1024] f32  (codebook abs-sum scratch, unused)
// 270352 : cb_bf16[1024*256] ushort (RTNE bf16 codebook, B-FRAGMENT order)
#define WS_SE    16
#define WS_SACB  4112
#define WS_CBBF  270352

typedef __attribute__((ext_vector_type(8))) short  short8;
typedef __attribute__((ext_vector_type(4))) float  f32x4;

__device__ __forceinline__ unsigned short bf16rtne(float f){
    unsigned int u = __float_as_uint(f);
    return (unsigned short)((u + 0x7FFFu + ((u >> 16) & 1u)) >> 16);
}

__global__ void init_ws(double* acc) {
    if (threadIdx.x == 0 && blockIdx.x == 0) *acc = 0.0;
}

// Bit-exact numpy pairwise_sum replication for sum(x^2) per row, plus an
// order-free sum(|x|). Used for the codebook (se); x row sums are fused
// into vq_score with the identical instruction sequence.
__global__ void rowsq_kernel(const float* __restrict__ src,
                             float* __restrict__ dst,
                             float* __restrict__ dst_abs, int nrows) {
    const int gtid = blockIdx.x * blockDim.x + threadIdx.x;
    const int wave = gtid >> 6;
    const int lane = threadIdx.x & 63;
    const int rowsub = lane >> 4;
    const int agent  = lane & 15;
    const int half   = agent >> 3;
    const int j      = agent & 7;
    const int row = wave * 4 + rowsub;
    if (row >= nrows) return;

    const float* p = src + (size_t)row * DIM + half * 128 + j;
    float x0 = p[0];
    float r  = __fmul_rn(x0, x0);
    float ra = fabsf(x0);
    #pragma unroll
    for (int i = 1; i < 16; ++i) {
        float xi = p[8 * i];
        r  = __fadd_rn(r, __fmul_rn(xi, xi));
        ra += fabsf(xi);
    }
    r = __fadd_rn(r, __shfl_xor(r, 1, 64));  ra += __shfl_xor(ra, 1, 64);
    r = __fadd_rn(r, __shfl_xor(r, 2, 64));  ra += __shfl_xor(ra, 2, 64);
    r = __fadd_rn(r, __shfl_xor(r, 4, 64));  ra += __shfl_xor(ra, 4, 64);
    r = __fadd_rn(r, __shfl_xor(r, 8, 64));  ra += __shfl_xor(ra, 8, 64);
    if (agent == 0) { dst[row] = r; dst_abs[row] = ra; }
}

// Codebook -> bf16 in MFMA B-fragment order:
//   dst[((T*8+s)*64 + lane)*8 + e] = bf16(cb[(T*16 + (lane&15))*256 + s*32 + (lane>>4)*8 + e])
// so a wave's load for (tile T, k-step s) is one contiguous 1 KB dwordx4.
__global__ void cvt_cb_kernel(const float* __restrict__ cb,
                              unsigned short* __restrict__ dst) {
    int o = blockIdx.x * 256 + threadIdx.x;   // 0..32767 short8 units
    int lane = o & 63;
    int ts   = o >> 6;                        // T*8 + s
    int code = (ts >> 3) * 16 + (lane & 15);
    int k0   = (ts & 7) * 32 + (lane >> 4) * 8;
    const float4* p = (const float4*)(cb + (size_t)code * DIM + k0);
    float4 a = p[0], b = p[1];
    short8 f;
    f[0] = (short)bf16rtne(a.x); f[1] = (short)bf16rtne(a.y);
    f[2] = (short)bf16rtne(a.z); f[3] = (short)bf16rtne(a.w);
    f[4] = (short)bf16rtne(b.x); f[5] = (short)bf16rtne(b.y);
    f[6] = (short)bf16rtne(b.z); f[7] = (short)bf16rtne(b.w);
    *(short8*)(dst + (size_t)o * 8) = f;
}

#define FMA4(A, X, E) do {                                       \
    A.x = fmaf(X.x, E.x, A.x); A.y = fmaf(X.y, E.y, A.y);        \
    A.z = fmaf(X.z, E.z, A.z); A.w = fmaf(X.w, E.w, A.w);        \
} while (0)

// 1024 blocks x 4 waves, 32 rows/block. Each wave: all 32 rows as bf16
// A-frags in regs; private 256-code slice; B-frags streamed coalesced from
// the fragment-ordered codebook with 2-deep register double buffering.
// Pass A: min tracking. Pass B: deterministic recompute, emit candidates
// within rigorous bf16-error margin. Pass C: exact fp32 rescore (verified
// bit-exact chain). np-exact sx/sa computed in-block (fused rowsq).
__launch_bounds__(256, 3)
__global__ void vq_score(const float* __restrict__ x,
                         const float* __restrict__ cb,
                         const float* __restrict__ se_arr,
                         const unsigned short* __restrict__ cbbf,
                         float* __restrict__ out_q,
                         float* __restrict__ out_idx,
                         double* __restrict__ loss_acc)
{
    __shared__ float minw[4][RPB];
    __shared__ float thr[RPB];
    __shared__ float sxl[RPB];
    __shared__ float sal[RPB];
    __shared__ unsigned int cnt[RPB];
    __shared__ unsigned int cand[RPB][CANDC];
    __shared__ unsigned long long win[RPB];
    __shared__ unsigned int wcode[RPB];

    const int tid  = threadIdx.x;
    const int w    = tid >> 6;
    const int lane = tid & 63;
    const int cc   = lane & 15;
    const int g    = lane >> 4;
    const int n0   = blockIdx.x * RPB;

    if (tid < RPB) { cnt[tid] = 0u; win[tid] = ~0ull; }

    // ---- A fragments: rows rt*16+cc, k = 32s + 8g + e (verified mapping) ----
    short8 afrag[2][8];
    #pragma unroll
    for (int rt = 0; rt < 2; ++rt) {
        const float4* rp = (const float4*)x + (size_t)(n0 + rt * 16 + cc) * 64;
        #pragma unroll
        for (int s = 0; s < 8; ++s) {
            float4 a = rp[s * 8 + g * 2];
            float4 b = rp[s * 8 + g * 2 + 1];
            short8 f;
            f[0] = (short)bf16rtne(a.x); f[1] = (short)bf16rtne(a.y);
            f[2] = (short)bf16rtne(a.z); f[3] = (short)bf16rtne(a.w);
            f[4] = (short)bf16rtne(b.x); f[5] = (short)bf16rtne(b.y);
            f[6] = (short)bf16rtne(b.z); f[7] = (short)bf16rtne(b.w);
            afrag[rt][s] = f;
        }
    }

    // ---- fused np-exact row sums (identical instruction sequence) ----
    {
        const int rowsub = lane >> 4;
        const int agent  = lane & 15;
        const int half   = agent >> 3;
        const int j      = agent & 7;
        #pragma unroll
        for (int q = 0; q < 2; ++q) {
            const int lrow = w * 8 + q * 4 + rowsub;
            const float* p = x + (size_t)(n0 + lrow) * DIM + half * 128 + j;
            float x0 = p[0];
            float r  = __fmul_rn(x0, x0);
            float ra = fabsf(x0);
            #pragma unroll
            for (int i = 1; i < 16; ++i) {
                float xi = p[8 * i];
                r  = __fadd_rn(r, __fmul_rn(xi, xi));
                ra += fabsf(xi);
            }
            r = __fadd_rn(r, __shfl_xor(r, 1, 64));  ra += __shfl_xor(ra, 1, 64);
            r = __fadd_rn(r, __shfl_xor(r, 2, 64));  ra += __shfl_xor(ra, 2, 64);
            r = __fadd_rn(r, __shfl_xor(r, 4, 64));  ra += __shfl_xor(ra, 4, 64);
            r = __fadd_rn(r, __shfl_xor(r, 8, 64));  ra += __shfl_xor(ra, 8, 64);
            if (agent == 0) { sxl[lrow] = r; sal[lrow] = ra; }
        }
    }

    const int T0 = w << 4;        // wave's first 16-code tile index
    const f32x4 fz = {0.f, 0.f, 0.f, 0.f};

    #define LOADB(T, dst) do {                                               \
        const char* bp_ = (const char*)cbbf + (size_t)(T) * 8192 + lane * 16;\
        _Pragma("unroll")                                                    \
        for (int s_ = 0; s_ < 8; ++s_)                                       \
            dst[s_] = *(const short8*)(bp_ + s_ * 1024);                     \
    } while (0)

    #define DOTS(bv, a0, a1) do {                                            \
        _Pragma("unroll")                                                    \
        for (int s_ = 0; s_ < 8; ++s_) {                                     \
            a0 = __builtin_amdgcn_mfma_f32_16x16x32_bf16(afrag[0][s_], bv[s_], a0, 0, 0, 0); \
            a1 = __builtin_amdgcn_mfma_f32_16x16x32_bf16(afrag[1][s_], bv[s_], a1, 0, 0, 0); \
        }                                                                    \
    } while (0)

    // ---- PASS A: score all codes, track per-lane running min ----
    float minr[2][4];
    #pragma unroll
    for (int rt = 0; rt < 2; ++rt)
        #pragma unroll
        for (int r = 0; r < 4; ++r) minr[rt][r] = INFINITY;

    {
        short8 bv[8], bn[8];
        LOADB(T0, bv);
        #pragma unroll 2
        for (int t = 0; t < 16; t += 2) {
            LOADB(T0 + t + 1, bn);
            {
                f32x4 a0 = fz, a1 = fz;
                DOTS(bv, a0, a1);
                const float sec = se_arr[(T0 + t) * 16 + cc];
                #pragma unroll
                for (int r = 0; r < 4; ++r) {
                    minr[0][r] = fminf(minr[0][r], fmaf(-2.f, a0[r], sec));
                    minr[1][r] = fminf(minr[1][r], fmaf(-2.f, a1[r], sec));
                }
            }
            if (t + 2 < 16) LOADB(T0 + t + 2, bv);
            {
                f32x4 a0 = fz, a1 = fz;
                DOTS(bn, a0, a1);
                const float sec = se_arr[(T0 + t + 1) * 16 + cc];
                #pragma unroll
                for (int r = 0; r < 4; ++r) {
                    minr[0][r] = fminf(minr[0][r], fmaf(-2.f, a0[r], sec));
                    minr[1][r] = fminf(minr[1][r], fmaf(-2.f, a1[r], sec));
                }
            }
        }
    }

    // reduce min across the 16 cc-lanes (row = rt*16 + 4g + r)
    #pragma unroll
    for (int rt = 0; rt < 2; ++rt) {
        #pragma unroll
        for (int r = 0; r < 4; ++r) {
            float v = minr[rt][r];
            v = fminf(v, __shfl_xor(v, 1, 64));
            v = fminf(v, __shfl_xor(v, 2, 64));
            v = fminf(v, __shfl_xor(v, 4, 64));
            v = fminf(v, __shfl_xor(v, 8, 64));
            if (cc == 0) minw[w][rt * 16 + g * 4 + r] = v;
        }
    }
    __syncthreads();
    if (tid < RPB) {
        float mm = fminf(fminf(minw[0][tid], minw[1][tid]),
                         fminf(minw[2][tid], minw[3][tid]));
        // margin: 2*(bf16 input-quant dot error, <= sa*7.7e-6) + f32 chain ulp slack
        thr[tid] = mm + fmaf(sal[tid], 1.6e-5f, 1.0e-4f);
    }
    __syncthreads();

    // ---- PASS B: deterministic recompute, emit candidates <= thr ----
    {
        float th[2][4];
        #pragma unroll
        for (int rt = 0; rt < 2; ++rt)
            #pragma unroll
            for (int r = 0; r < 4; ++r) th[rt][r] = thr[rt * 16 + g * 4 + r];

        short8 bv[8], bn[8];
        LOADB(T0, bv);
        #pragma unroll 2
        for (int t = 0; t < 16; t += 2) {
            LOADB(T0 + t + 1, bn);
            #pragma unroll
            for (int half = 0; half < 2; ++half) {
                f32x4 a0 = fz, a1 = fz;
                if (half == 0) { DOTS(bv, a0, a1); }
                else          { DOTS(bn, a0, a1); }
                const int cbase = (T0 + t + half) * 16;
                const float sec = se_arr[cbase + cc];
                #pragma unroll
                for (int r = 0; r < 4; ++r) {
                    float s0 = fmaf(-2.f, a0[r], sec);
                    float s1 = fmaf(-2.f, a1[r], sec);
                    if (s0 <= th[0][r]) {
                        int row = g * 4 + r;
                        unsigned int p = atomicAdd(&cnt[row], 1u);
                        if (p < (unsigned)CANDC) cand[row][p] = (unsigned int)(cbase + cc);
                    }
                    if (s1 <= th[1][r]) {
                        int row = 16 + g * 4 + r;
                        unsigned int p = atomicAdd(&cnt[row], 1u);
                        if (p < (unsigned)CANDC) cand[row][p] = (unsigned int)(cbase + cc);
                    }
                }
                if (half == 0 && t + 2 < 16) LOADB(T0 + t + 2, bv);
            }
        }
    }
    __syncthreads();

    // ---- PASS C: exact fp32 rescore of candidates (tie -> lower code) ----
    {
        const int r  = tid >> 3;
        const int sl = tid & 7;
        const unsigned int n = cnt[r];
        const bool ovf = (n > (unsigned)CANDC);
        const unsigned int total = ovf ? (unsigned)KCODES : n;
        const float sxr = sxl[r];
        const float4* xr  = (const float4*)x + (size_t)(n0 + r) * 64;
        const float4* cb4 = (const float4*)cb;
        for (unsigned int j = sl; j < total; j += 8) {
            unsigned int code = ovf ? j : cand[r][j];
            const float4* er = cb4 + (size_t)code * 64;
            float4 a4 = make_float4(0.f, 0.f, 0.f, 0.f);
            #pragma unroll 8
            for (int m = 0; m < 64; ++m) {
                float4 xv = xr[m];
                float4 ev = er[m];
                FMA4(a4, xv, ev);
            }
            float dot  = (a4.x + a4.y) + (a4.z + a4.w);
            float tt   = __fadd_rn(sxr, se_arr[code]);
            float dist = __fsub_rn(tt, 2.0f * dot);
            unsigned long long pk =
                ((unsigned long long)__float_as_uint(dist) << 32) | (unsigned long long)code;
            atomicMin(&win[r], pk);
        }
    }
    __syncthreads();
    if (tid < RPB) {
        unsigned int code = (unsigned int)(win[tid] & 0xFFFFFFFFull);
        wcode[tid] = code;
        out_idx[n0 + tid] = (float)code;
    }
    __syncthreads();

    // ---- outputs (bit-exact straight-through) + fp64 loss partial ----
    double lacc = 0.0;
    {
        const float4* x4  = (const float4*)x;
        const float4* cb4 = (const float4*)cb;
        float4* q4 = (float4*)out_q;
        #pragma unroll
        for (int i = 0; i < 8; ++i) {
            int flat = tid + 256 * i;       // 0..2047 (32 rows x 64 float4)
            int row  = flat >> 6;
            int d4   = flat & 63;
            float4 xv = x4[(size_t)n0 * 64 + flat];
            float4 qv = cb4[(size_t)wcode[row] * 64 + d4];
            float dfx = __fsub_rn(qv.x, xv.x);
            float dfy = __fsub_rn(qv.y, xv.y);
            float dfz = __fsub_rn(qv.z, xv.z);
            float dfw = __fsub_rn(qv.w, xv.w);
            float4 o;
            o.x = __fadd_rn(xv.x, dfx);
            o.y = __fadd_rn(xv.y, dfy);
            o.z = __fadd_rn(xv.z, dfz);
            o.w = __fadd_rn(xv.w, dfw);
            lacc += (double)dfx * dfx + (double)dfy * dfy
                  + (double)dfz * dfz + (double)dfw * dfw;
            q4[(size_t)n0 * 64 + flat] = o;
        }
    }
    #pragma unroll
    for (int off = 32; off > 0; off >>= 1)
        lacc += __shfl_down(lacc, off, 64);
    if (lane == 0) atomicAdd(loss_acc, lacc);
}

__global__ void finalize_loss(const double* __restrict__ acc,
                              float* __restrict__ out_loss) {
    if (threadIdx.x == 0 && blockIdx.x == 0)
        *out_loss = (float)(*acc / (double)(NROWS * DIM));
}

extern "C" void kernel_launch(void* const* d_in, const int* in_sizes, int n_in,
                              void* d_out, int out_size, void* d_ws, size_t ws_size,
                              hipStream_t stream) {
    const float* x  = (const float*)d_in[0];
    const float* cb = (const float*)d_in[1];
    float* out      = (float*)d_out;
    float* out_q    = out;                        // 8388608 elements
    float* out_idx  = out + (size_t)NROWS * DIM;  // 32768 elements (as float)
    float* out_loss = out_idx + NROWS;            // 1 element

    char* ws = (char*)d_ws;
    double* acc = (double*)ws;
    float* se   = (float*)(ws + WS_SE);
    float* sacb = (float*)(ws + WS_SACB);
    unsigned short* cbbf = (unsigned short*)(ws + WS_CBBF);

    init_ws<<<1, 1, 0, stream>>>(acc);
    rowsq_kernel<<<KCODES / 16, 256, 0, stream>>>(cb, se, sacb, KCODES);
    cvt_cb_kernel<<<128, 256, 0, stream>>>(cb, cbbf);
    vq_score<<<NROWS / RPB, 256, 0, stream>>>(x, cb, se, cbbf,
                                              out_q, out_idx, acc);
    finalize_loss<<<1, 1, 0, stream>>>(acc, out_loss);
}

// Round 4
// 236.848 us; speedup vs baseline: 3.7005x; 1.1361x over previous
//
#include <hip/hip_runtime.h>
#include <math.h>

#define NROWS 32768
#define DIM   256
#define KCODES 1024
#define RPB   32      // rows per block
#define CANDC 12      // candidate cap per row

// ---- ws layout (bytes) ----
//      0 : double loss accumulator
//     16 : se[1024]   f32  (np-exact codebook row sum-of-squares)
//   4112 : sacb[1024] f32  (codebook abs-sum scratch, unused)
// 270352 : cb_bf16[1024*256] ushort (RTNE bf16 codebook, B-FRAGMENT order)
#define WS_SE    16
#define WS_SACB  4112
#define WS_CBBF  270352

typedef __attribute__((ext_vector_type(8))) short  short8;
typedef __attribute__((ext_vector_type(4))) float  f32x4;

__device__ __forceinline__ unsigned short bf16rtne(float f){
    unsigned int u = __float_as_uint(f);
    return (unsigned short)((u + 0x7FFFu + ((u >> 16) & 1u)) >> 16);
}

__device__ __forceinline__ void gload_lds16(const void* g, void* l){
    __builtin_amdgcn_global_load_lds(
        (const __attribute__((address_space(1))) void*)g,
        (__attribute__((address_space(3))) void*)l, 16, 0, 0);
}

__global__ void init_ws(double* acc) {
    if (threadIdx.x == 0 && blockIdx.x == 0) *acc = 0.0;
}

// Bit-exact numpy pairwise_sum replication for sum(x^2) per row, plus an
// order-free sum(|x|). Used for the codebook (se); x row sums are fused
// into vq_score with the identical instruction sequence.
__global__ void rowsq_kernel(const float* __restrict__ src,
                             float* __restrict__ dst,
                             float* __restrict__ dst_abs, int nrows) {
    const int gtid = blockIdx.x * blockDim.x + threadIdx.x;
    const int wave = gtid >> 6;
    const int lane = threadIdx.x & 63;
    const int rowsub = lane >> 4;
    const int agent  = lane & 15;
    const int half   = agent >> 3;
    const int j      = agent & 7;
    const int row = wave * 4 + rowsub;
    if (row >= nrows) return;

    const float* p = src + (size_t)row * DIM + half * 128 + j;
    float x0 = p[0];
    float r  = __fmul_rn(x0, x0);
    float ra = fabsf(x0);
    #pragma unroll
    for (int i = 1; i < 16; ++i) {
        float xi = p[8 * i];
        r  = __fadd_rn(r, __fmul_rn(xi, xi));
        ra += fabsf(xi);
    }
    r = __fadd_rn(r, __shfl_xor(r, 1, 64));  ra += __shfl_xor(ra, 1, 64);
    r = __fadd_rn(r, __shfl_xor(r, 2, 64));  ra += __shfl_xor(ra, 2, 64);
    r = __fadd_rn(r, __shfl_xor(r, 4, 64));  ra += __shfl_xor(ra, 4, 64);
    r = __fadd_rn(r, __shfl_xor(r, 8, 64));  ra += __shfl_xor(ra, 8, 64);
    if (agent == 0) { dst[row] = r; dst_abs[row] = ra; }
}

// Codebook -> bf16 in MFMA B-fragment order:
//   dst[((T*8+s)*64 + lane)*8 + e] = bf16(cb[(T*16 + (lane&15))*256 + s*32 + (lane>>4)*8 + e])
// so a wave's load for (tile T, k-step s) is one contiguous 1 KB chunk.
__global__ void cvt_cb_kernel(const float* __restrict__ cb,
                              unsigned short* __restrict__ dst) {
    int o = blockIdx.x * 256 + threadIdx.x;   // 0..32767 short8 units
    int lane = o & 63;
    int ts   = o >> 6;                        // T*8 + s
    int code = (ts >> 3) * 16 + (lane & 15);
    int k0   = (ts & 7) * 32 + (lane >> 4) * 8;
    const float4* p = (const float4*)(cb + (size_t)code * DIM + k0);
    float4 a = p[0], b = p[1];
    short8 f;
    f[0] = (short)bf16rtne(a.x); f[1] = (short)bf16rtne(a.y);
    f[2] = (short)bf16rtne(a.z); f[3] = (short)bf16rtne(a.w);
    f[4] = (short)bf16rtne(b.x); f[5] = (short)bf16rtne(b.y);
    f[6] = (short)bf16rtne(b.z); f[7] = (short)bf16rtne(b.w);
    *(short8*)(dst + (size_t)o * 8) = f;
}

#define FMA4(A, X, E) do {                                       \
    A.x = fmaf(X.x, E.x, A.x); A.y = fmaf(X.y, E.y, A.y);        \
    A.z = fmaf(X.z, E.z, A.z); A.w = fmaf(X.w, E.w, A.w);        \
} while (0)

// 1024 blocks x 4 waves, 32 rows/block. Wave-private LDS double-buffered
// B-streaming via global_load_lds (zero VGPR, compiler can't collapse it)
// with explicit counted vmcnt — NO barriers in the main loop. Pass A tracks
// global min + per-tile mins; only qualifying tiles are revisited in pass B
// (conservative filter; candidates verified by exact fp32 rescore, pass C).
__launch_bounds__(256, 2)
__global__ void vq_score(const float* __restrict__ x,
                         const float* __restrict__ cb,
                         const float* __restrict__ se_arr,
                         const unsigned short* __restrict__ cbbf,
                         float* __restrict__ out_q,
                         float* __restrict__ out_idx,
                         double* __restrict__ loss_acc)
{
    // wave-private double buffers: [wave][buf][k-step s][lane] = short8
    __shared__ short8 bufs[4][2][8][64];     // 65536 B
    __shared__ float minw[4][RPB];
    __shared__ float thr[RPB];
    __shared__ float sxl[RPB];
    __shared__ float sal[RPB];
    __shared__ unsigned int cnt[RPB];
    __shared__ unsigned int cand[RPB][CANDC];
    __shared__ unsigned long long win[RPB];
    __shared__ unsigned int wcode[RPB];

    const int tid  = threadIdx.x;
    const int w    = tid >> 6;
    const int lane = tid & 63;
    const int cc   = lane & 15;
    const int g    = lane >> 4;
    const int n0   = blockIdx.x * RPB;

    if (tid < RPB) { cnt[tid] = 0u; win[tid] = ~0ull; }

    // ---- A fragments: rows rt*16+cc, k = 32s + 8g + e (verified mapping) ----
    short8 afrag[2][8];
    #pragma unroll
    for (int rt = 0; rt < 2; ++rt) {
        const float4* rp = (const float4*)x + (size_t)(n0 + rt * 16 + cc) * 64;
        #pragma unroll
        for (int s = 0; s < 8; ++s) {
            float4 a = rp[s * 8 + g * 2];
            float4 b = rp[s * 8 + g * 2 + 1];
            short8 f;
            f[0] = (short)bf16rtne(a.x); f[1] = (short)bf16rtne(a.y);
            f[2] = (short)bf16rtne(a.z); f[3] = (short)bf16rtne(a.w);
            f[4] = (short)bf16rtne(b.x); f[5] = (short)bf16rtne(b.y);
            f[6] = (short)bf16rtne(b.z); f[7] = (short)bf16rtne(b.w);
            afrag[rt][s] = f;
        }
    }

    // ---- fused np-exact row sums (identical instruction sequence) ----
    {
        const int rowsub = lane >> 4;
        const int agent  = lane & 15;
        const int half   = agent >> 3;
        const int j      = agent & 7;
        #pragma unroll
        for (int q = 0; q < 2; ++q) {
            const int lrow = w * 8 + q * 4 + rowsub;
            const float* p = x + (size_t)(n0 + lrow) * DIM + half * 128 + j;
            float x0 = p[0];
            float r  = __fmul_rn(x0, x0);
            float ra = fabsf(x0);
            #pragma unroll
            for (int i = 1; i < 16; ++i) {
                float xi = p[8 * i];
                r  = __fadd_rn(r, __fmul_rn(xi, xi));
                ra += fabsf(xi);
            }
            r = __fadd_rn(r, __shfl_xor(r, 1, 64));  ra += __shfl_xor(ra, 1, 64);
            r = __fadd_rn(r, __shfl_xor(r, 2, 64));  ra += __shfl_xor(ra, 2, 64);
            r = __fadd_rn(r, __shfl_xor(r, 4, 64));  ra += __shfl_xor(ra, 4, 64);
            r = __fadd_rn(r, __shfl_xor(r, 8, 64));  ra += __shfl_xor(ra, 8, 64);
            if (agent == 0) { sxl[lrow] = r; sal[lrow] = ra; }
        }
    }

    const int T0 = w << 4;        // wave's first 16-code tile index
    const f32x4 fz = {0.f, 0.f, 0.f, 0.f};

    // se values for the wave's 256-code slice, statically-indexed registers
    // (keeps the counted-vmcnt region free of stray VMEM ops)
    float se_reg[16];
    #pragma unroll
    for (int t = 0; t < 16; ++t) se_reg[t] = se_arr[(T0 + t) * 16 + cc];

    float minr[2][4];
    #pragma unroll
    for (int rt = 0; rt < 2; ++rt)
        #pragma unroll
        for (int r = 0; r < 4; ++r) minr[rt][r] = INFINITY;
    float tilemin[16];

#define ISSUE(T) do {                                                         \
    const char* gsrc_ = (const char*)cbbf + (size_t)(T0 + (T)) * 8192 + lane * 16; \
    _Pragma("unroll")                                                         \
    for (int i_ = 0; i_ < 8; ++i_)                                            \
        gload_lds16(gsrc_ + i_ * 1024, (void*)&bufs[w][(T) & 1][i_][0]);      \
} while (0)

#define WAITV_(N) asm volatile("s_waitcnt vmcnt(" #N ")" ::: "memory")
#define WAITV(N) WAITV_(N)
#define LGKM0 asm volatile("s_waitcnt lgkmcnt(0)" ::: "memory")

#define COMPUTE(T) do {                                                       \
    short8 bv_[8];                                                            \
    _Pragma("unroll")                                                         \
    for (int s_ = 0; s_ < 8; ++s_) bv_[s_] = bufs[w][(T) & 1][s_][lane];      \
    f32x4 a0_ = fz, a1_ = fz;                                                 \
    _Pragma("unroll")                                                         \
    for (int s_ = 0; s_ < 8; ++s_) {                                          \
        a0_ = __builtin_amdgcn_mfma_f32_16x16x32_bf16(afrag[0][s_], bv_[s_], a0_, 0, 0, 0); \
        a1_ = __builtin_amdgcn_mfma_f32_16x16x32_bf16(afrag[1][s_], bv_[s_], a1_, 0, 0, 0); \
    }                                                                         \
    const float sec_ = se_reg[(T)];                                           \
    float tm_ = INFINITY;                                                     \
    _Pragma("unroll")                                                         \
    for (int r_ = 0; r_ < 4; ++r_) {                                          \
        float s0_ = fmaf(-2.f, a0_[r_], sec_);                                \
        float s1_ = fmaf(-2.f, a1_[r_], sec_);                                \
        minr[0][r_] = fminf(minr[0][r_], s0_);                                \
        minr[1][r_] = fminf(minr[1][r_], s1_);                                \
        tm_ = fminf(tm_, fminf(s0_, s1_));                                    \
    }                                                                         \
    tilemin[(T)] = tm_;                                                       \
} while (0)

// lgkmcnt(0): previous tile's ds_reads must land before overwriting its buf.
#define STEPW(T, W) do {                                                      \
    LGKM0;                                                                    \
    if ((T) < 15) ISSUE((T) + 1);                                             \
    WAITV(W);                                                                 \
    COMPUTE(T);                                                               \
} while (0)

    // ---- PASS A: counted-vmcnt pipelined scoring, no barriers ----
    WAITV(0);              // drain pre-loop VMEM so counts are exact
    ISSUE(0);
    STEPW(0, 8);  STEPW(1, 8);  STEPW(2, 8);  STEPW(3, 8);
    STEPW(4, 8);  STEPW(5, 8);  STEPW(6, 8);  STEPW(7, 8);
    STEPW(8, 8);  STEPW(9, 8);  STEPW(10, 8); STEPW(11, 8);
    STEPW(12, 8); STEPW(13, 8); STEPW(14, 8); STEPW(15, 0);

    // reduce min across the 16 cc-lanes (row = rt*16 + 4g + r)
    #pragma unroll
    for (int rt = 0; rt < 2; ++rt) {
        #pragma unroll
        for (int r = 0; r < 4; ++r) {
            float v = minr[rt][r];
            v = fminf(v, __shfl_xor(v, 1, 64));
            v = fminf(v, __shfl_xor(v, 2, 64));
            v = fminf(v, __shfl_xor(v, 4, 64));
            v = fminf(v, __shfl_xor(v, 8, 64));
            if (cc == 0) minw[w][rt * 16 + g * 4 + r] = v;
        }
    }
    __syncthreads();
    if (tid < RPB) {
        float mm = fminf(fminf(minw[0][tid], minw[1][tid]),
                         fminf(minw[2][tid], minw[3][tid]));
        // margin: 2*(bf16 input-quant dot error, <= sa*7.7e-6) + f32 chain ulp slack
        thr[tid] = mm + fmaf(sal[tid], 1.6e-5f, 1.0e-4f);
    }
    __syncthreads();

    // ---- tile qualification + PASS B over qualifying tiles only ----
    {
        float th[2][4];
        #pragma unroll
        for (int rt = 0; rt < 2; ++rt)
            #pragma unroll
            for (int r = 0; r < 4; ++r) th[rt][r] = thr[rt * 16 + g * 4 + r];
        float mymax = th[0][0];
        #pragma unroll
        for (int rt = 0; rt < 2; ++rt)
            #pragma unroll
            for (int r = 0; r < 4; ++r) mymax = fmaxf(mymax, th[rt][r]);

        unsigned int qmask = 0;
        #pragma unroll
        for (int t = 0; t < 16; ++t)
            if (__any(tilemin[t] <= mymax)) qmask |= (1u << t);

        unsigned int m = qmask;   // wave-uniform
        while (m) {
            int t = __ffs(m) - 1;
            m &= m - 1;
            short8 bv[8];
            const char* bp = (const char*)cbbf + (size_t)(T0 + t) * 8192 + lane * 16;
            #pragma unroll
            for (int s_ = 0; s_ < 8; ++s_)
                bv[s_] = *(const short8*)(bp + s_ * 1024);
            f32x4 a0 = fz, a1 = fz;
            #pragma unroll
            for (int s_ = 0; s_ < 8; ++s_) {
                a0 = __builtin_amdgcn_mfma_f32_16x16x32_bf16(afrag[0][s_], bv[s_], a0, 0, 0, 0);
                a1 = __builtin_amdgcn_mfma_f32_16x16x32_bf16(afrag[1][s_], bv[s_], a1, 0, 0, 0);
            }
            const int cbase = (T0 + t) * 16;
            const float sec = se_arr[cbase + cc];
            #pragma unroll
            for (int r = 0; r < 4; ++r) {
                float s0 = fmaf(-2.f, a0[r], sec);
                float s1 = fmaf(-2.f, a1[r], sec);
                if (s0 <= th[0][r]) {
                    int row = g * 4 + r;
                    unsigned int p = atomicAdd(&cnt[row], 1u);
                    if (p < (unsigned)CANDC) cand[row][p] = (unsigned int)(cbase + cc);
                }
                if (s1 <= th[1][r]) {
                    int row = 16 + g * 4 + r;
                    unsigned int p = atomicAdd(&cnt[row], 1u);
                    if (p < (unsigned)CANDC) cand[row][p] = (unsigned int)(cbase + cc);
                }
            }
        }
    }
    __syncthreads();

    // ---- PASS C: exact fp32 rescore of candidates (tie -> lower code) ----
    {
        const int r  = tid >> 3;
        const int sl = tid & 7;
        const unsigned int n = cnt[r];
        const bool ovf = (n > (unsigned)CANDC);
        const unsigned int total = ovf ? (unsigned)KCODES : n;
        const float sxr = sxl[r];
        const float4* xr  = (const float4*)x + (size_t)(n0 + r) * 64;
        const float4* cb4 = (const float4*)cb;
        for (unsigned int j = sl; j < total; j += 8) {
            unsigned int code = ovf ? j : cand[r][j];
            const float4* er = cb4 + (size_t)code * 64;
            float4 a4 = make_float4(0.f, 0.f, 0.f, 0.f);
            #pragma unroll 8
            for (int m2 = 0; m2 < 64; ++m2) {
                float4 xv = xr[m2];
                float4 ev = er[m2];
                FMA4(a4, xv, ev);
            }
            float dot  = (a4.x + a4.y) + (a4.z + a4.w);
            float tt   = __fadd_rn(sxr, se_arr[code]);
            float dist = __fsub_rn(tt, 2.0f * dot);
            unsigned long long pk =
                ((unsigned long long)__float_as_uint(dist) << 32) | (unsigned long long)code;
            atomicMin(&win[r], pk);
        }
    }
    __syncthreads();
    if (tid < RPB) {
        unsigned int code = (unsigned int)(win[tid] & 0xFFFFFFFFull);
        wcode[tid] = code;
        out_idx[n0 + tid] = (float)code;
    }
    __syncthreads();

    // ---- outputs (bit-exact straight-through) + fp64 loss partial ----
    double lacc = 0.0;
    {
        const float4* x4  = (const float4*)x;
        const float4* cb4 = (const float4*)cb;
        float4* q4 = (float4*)out_q;
        #pragma unroll
        for (int i = 0; i < 8; ++i) {
            int flat = tid + 256 * i;       // 0..2047 (32 rows x 64 float4)
            int row  = flat >> 6;
            int d4   = flat & 63;
            float4 xv = x4[(size_t)n0 * 64 + flat];
            float4 qv = cb4[(size_t)wcode[row] * 64 + d4];
            float dfx = __fsub_rn(qv.x, xv.x);
            float dfy = __fsub_rn(qv.y, xv.y);
            float dfz = __fsub_rn(qv.z, xv.z);
            float dfw = __fsub_rn(qv.w, xv.w);
            float4 o;
            o.x = __fadd_rn(xv.x, dfx);
            o.y = __fadd_rn(xv.y, dfy);
            o.z = __fadd_rn(xv.z, dfz);
            o.w = __fadd_rn(xv.w, dfw);
            lacc += (double)dfx * dfx + (double)dfy * dfy
                  + (double)dfz * dfz + (double)dfw * dfw;
            q4[(size_t)n0 * 64 + flat] = o;
        }
    }
    #pragma unroll
    for (int off = 32; off > 0; off >>= 1)
        lacc += __shfl_down(lacc, off, 64);
    if (lane == 0) atomicAdd(loss_acc, lacc);
}

__global__ void finalize_loss(const double* __restrict__ acc,
                              float* __restrict__ out_loss) {
    if (threadIdx.x == 0 && blockIdx.x == 0)
        *out_loss = (float)(*acc / (double)(NROWS * DIM));
}

extern "C" void kernel_launch(void* const* d_in, const int* in_sizes, int n_in,
                              void* d_out, int out_size, void* d_ws, size_t ws_size,
                              hipStream_t stream) {
    const float* x  = (const float*)d_in[0];
    const float* cb = (const float*)d_in[1];
    float* out      = (float*)d_out;
    float* out_q    = out;                        // 8388608 elements
    float* out_idx  = out + (size_t)NROWS * DIM;  // 32768 elements (as float)
    float* out_loss = out_idx + NROWS;            // 1 element

    char* ws = (char*)d_ws;
    double* acc = (double*)ws;
    float* se   = (float*)(ws + WS_SE);
    float* sacb = (float*)(ws + WS_SACB);
    unsigned short* cbbf = (unsigned short*)(ws + WS_CBBF);

    init_ws<<<1, 1, 0, stream>>>(acc);
    rowsq_kernel<<<KCODES / 16, 256, 0, stream>>>(cb, se, sacb, KCODES);
    cvt_cb_kernel<<<128, 256, 0, stream>>>(cb, cbbf);
    vq_score<<<NROWS / RPB, 256, 0, stream>>>(x, cb, se, cbbf,
                                              out_q, out_idx, acc);
    finalize_loss<<<1, 1, 0, stream>>>(acc, out_loss);
}